// Round 2
// baseline (1349.283 us; speedup 1.0000x reference)
//
#include <hip/hip_runtime.h>
#include <math.h>

#define N_IN 8192
#define N_MC 32768
#define K_SEL 656
#define RPB 8      // rows per block in overlap kernel
#define TPB 256

// Kernel 1: eff[row] = exp(neigh[row]-duty[row]) * popcount(perm[row,:] >= 0.5 & I)
// Memory-bound: streams 1 GiB of permanences. One block handles RPB rows;
// each thread covers 32 columns (8 float4 chunks), I slice preloaded to regs.
__global__ __launch_bounds__(TPB) void overlap_kernel(
    const int* __restrict__ I,
    const float* __restrict__ perm,
    const float* __restrict__ duty,
    const float* __restrict__ neigh,
    float* __restrict__ eff)
{
  const int t = threadIdx.x;
  const int row0 = blockIdx.x * RPB;

  // Thread t covers float4-chunks c = k*TPB + t (elements 4c..4c+3).
  // I is loop-invariant across rows: load once into registers as 0/1 floats.
  float iv[32];
#pragma unroll
  for (int k = 0; k < 8; ++k) {
    const int c = k * TPB + t;
    const int4 r = *reinterpret_cast<const int4*>(I + 4 * c);
    iv[4*k+0] = r.x ? 1.0f : 0.0f;
    iv[4*k+1] = r.y ? 1.0f : 0.0f;
    iv[4*k+2] = r.z ? 1.0f : 0.0f;
    iv[4*k+3] = r.w ? 1.0f : 0.0f;
  }

  int cnt[RPB];
#pragma unroll
  for (int r = 0; r < RPB; ++r) cnt[r] = 0;

  for (int r = 0; r < RPB; ++r) {
    const float* prow = perm + (size_t)(row0 + r) * N_IN;
#pragma unroll
    for (int k = 0; k < 8; ++k) {
      const int c = k * TPB + t;
      const float4 p = *reinterpret_cast<const float4*>(prow + 4 * c);
      // iv in {0,1}: p*iv >= 0.5 <=> (perm >= 0.5 && I) ; exact (mul by 0/1).
      cnt[r] += (p.x * iv[4*k+0] >= 0.5f) ? 1 : 0;
      cnt[r] += (p.y * iv[4*k+1] >= 0.5f) ? 1 : 0;
      cnt[r] += (p.z * iv[4*k+2] >= 0.5f) ? 1 : 0;
      cnt[r] += (p.w * iv[4*k+3] >= 0.5f) ? 1 : 0;
    }
  }

  __shared__ int s_part[4][RPB];
  const int lane = t & 63;
  const int wave = t >> 6;
#pragma unroll
  for (int r = 0; r < RPB; ++r) {
    int v = cnt[r];
#pragma unroll
    for (int off = 32; off > 0; off >>= 1) v += __shfl_xor(v, off, 64);
    if (lane == 0) s_part[wave][r] = v;
  }
  __syncthreads();
  if (t < RPB) {
    const int row = row0 + t;
    const int total = s_part[0][t] + s_part[1][t] + s_part[2][t] + s_part[3][t];
    const float d = neigh[row] - duty[row];             // f32 sub, as in ref
    const float boost = (float)exp((double)d);          // correctly-rounded f32 exp
    eff[row] = boost * (float)total;                    // f32 product, as in ref
  }
}

// Kernel 2: exact top-K mask over 32768 non-negative floats, single block.
// Bitwise binary search on the (monotonic) float bit pattern for the K-th
// largest value; ties at the threshold resolved by lowest index (stable block
// scan) to match jax.lax.top_k. Output is int32 0/1 (bool ref -> int32 path
// in the harness; round-1 absmax 0x3F800000-1 proved selection was already
// exact and only the store dtype was wrong).
__global__ __launch_bounds__(1024) void select_kernel(
    const float* __restrict__ eff, int* __restrict__ out)
{
  const int t = threadIdx.x;
  const int lane = t & 63;
  const int wave = t >> 6;  // 0..15

  // Thread t owns consecutive indices [t*32, t*32+32) -> stable index order.
  unsigned key[32];
  {
    const uint4* kp = reinterpret_cast<const uint4*>(eff) + t * 8;
#pragma unroll
    for (int k = 0; k < 8; ++k) {
      const uint4 v = kp[k];
      key[4*k+0] = v.x; key[4*k+1] = v.y; key[4*k+2] = v.z; key[4*k+3] = v.w;
    }
  }

  __shared__ int s_cnt[16];
  __shared__ unsigned s_u;
  __shared__ int s_need;
  __shared__ int s_scan[1024];

  // Greedy MSB->LSB: largest p with count(key >= p) >= K  ==  K-th largest.
  unsigned p = 0;
  for (int bit = 30; bit >= 0; --bit) {   // bit31 (sign) is 0 for all keys
    const unsigned cand = p | (1u << bit);
    int c = 0;
#pragma unroll
    for (int e = 0; e < 32; ++e) c += (key[e] >= cand) ? 1 : 0;
#pragma unroll
    for (int off = 32; off > 0; off >>= 1) c += __shfl_xor(c, off, 64);
    if (lane == 0) s_cnt[wave] = c;
    __syncthreads();
    if (t == 0) {
      int tot = 0;
#pragma unroll
      for (int w = 0; w < 16; ++w) tot += s_cnt[w];
      s_u = (tot >= K_SEL) ? cand : p;
    }
    __syncthreads();
    p = s_u;
  }
  const unsigned thr = p;

  // Count strictly-greater -> how many equals we still need (by lowest index).
  {
    int c = 0;
#pragma unroll
    for (int e = 0; e < 32; ++e) c += (key[e] > thr) ? 1 : 0;
#pragma unroll
    for (int off = 32; off > 0; off >>= 1) c += __shfl_xor(c, off, 64);
    if (lane == 0) s_cnt[wave] = c;
  }
  __syncthreads();
  if (t == 0) {
    int tot = 0;
#pragma unroll
    for (int w = 0; w < 16; ++w) tot += s_cnt[w];
    s_need = K_SEL - tot;   // >= 1 by construction
  }

  int myeq = 0;
#pragma unroll
  for (int e = 0; e < 32; ++e) myeq += (key[e] == thr) ? 1 : 0;
  s_scan[t] = myeq;
  __syncthreads();
  const int need_eq = s_need;
  // Hillis-Steele inclusive scan over 1024 per-thread equal-counts.
  for (int off = 1; off < 1024; off <<= 1) {
    const int v = s_scan[t];
    const int add = (t >= off) ? s_scan[t - off] : 0;
    __syncthreads();
    s_scan[t] = v + add;
    __syncthreads();
  }
  int rank = s_scan[t] - myeq;  // exclusive rank of this thread's first equal

  int o[32];
#pragma unroll
  for (int e = 0; e < 32; ++e) {
    bool sel = key[e] > thr;
    if (key[e] == thr) { sel = (rank < need_eq); ++rank; }
    o[e] = sel ? 1 : 0;
  }
  int4* op = reinterpret_cast<int4*>(out) + t * 8;
#pragma unroll
  for (int k = 0; k < 8; ++k)
    op[k] = make_int4(o[4*k+0], o[4*k+1], o[4*k+2], o[4*k+3]);
}

extern "C" void kernel_launch(void* const* d_in, const int* in_sizes, int n_in,
                              void* d_out, int out_size, void* d_ws, size_t ws_size,
                              hipStream_t stream) {
  const int*   I     = (const int*)d_in[0];
  const float* perm  = (const float*)d_in[1];
  const float* duty  = (const float*)d_in[2];
  const float* neigh = (const float*)d_in[3];
  int* out = (int*)d_out;
  float* eff = (float*)d_ws;   // 32768 floats = 128 KB scratch

  hipLaunchKernelGGL(overlap_kernel, dim3(N_MC / RPB), dim3(TPB), 0, stream,
                     I, perm, duty, neigh, eff);
  hipLaunchKernelGGL(select_kernel, dim3(1), dim3(1024), 0, stream, eff, out);
}